// Round 10
// baseline (891.333 us; speedup 1.0000x reference)
//
#include <hip/hip_runtime.h>
#include <cmath>

#define WS 11
#define IMH 512
#define IMW 512
#define OH 502
#define OW 502
#define NPLANES 96                 // 32 * 3
#define STRIPW 48                  // output cols per wave strip
#define STRIPH 64                  // output rows per wave strip (4 subs x 16)
#define SUBH 16                    // rows per lane
#define XSTRIPS 11                 // ceil(502/48)
#define YSTRIPS 8                  // ceil(502/64)
#define NTASKS (XSTRIPS * YSTRIPS * NPLANES)   // 8448
#define WPB 4                      // waves per block (256 threads), 1 strip/wave
#define NBLK (NTASKS / WPB)        // 2112
#define NOUT ((long long)NPLANES * OH * OW)    // 24192384

typedef float f32x4 __attribute__((ext_vector_type(4)));

struct GaussW { float g[WS]; };

// ---------------- kernel 1: range-detection flags over img1 ----------------
__global__ __launch_bounds__(256) void flags_kernel(const float* __restrict__ img1,
                                                    unsigned* __restrict__ flags,
                                                    int n4) {
    int idx = blockIdx.x * blockDim.x + threadIdx.x;
    int stride = gridDim.x * blockDim.x;
    int gt = 0, lt = 0;
    const float4* p = reinterpret_cast<const float4*>(img1);
    for (int i = idx; i < n4; i += stride) {
        float4 v = p[i];
        gt |= (v.x > 128.f) | (v.y > 128.f) | (v.z > 128.f) | (v.w > 128.f);
        lt |= (v.x < -0.5f) | (v.y < -0.5f) | (v.z < -0.5f) | (v.w < -0.5f);
    }
    if (gt) atomicOr(&flags[0], 1u);
    if (lt) atomicOr(&flags[1], 1u);
}

// ---------------- kernel 2: LDS-free register-ring SSIM, 4-quantity form ----
// One strip (48x64) per wave; 4 independent waves per 256-thread block
// (raises dispatch-limited residency 2x vs 128-thread blocks). Lane
// (g = lane&15, s = lane>>4) streams col-group [4g..4g+3] down 16 rows with
// an 11-row register ring of s = x+y, d = x-y; row loop fully unrolled
// (ring in registers, 2 b128 loads/iter). NO outer strip loop (R9 lesson:
// it blew VGPR 112->176). All 40 horizontal shuffles issued back-to-back
// before any consuming FMA so lgkmcnt waits drain under FMA issue.
__global__ __launch_bounds__(256, 4) void ssim_kernel(const float* __restrict__ img1,
                                                      const float* __restrict__ img2,
                                                      const unsigned* __restrict__ flags,
                                                      double* __restrict__ sum_out,
                                                      double* __restrict__ partials,
                                                      int use_partials,
                                                      GaussW gw) {
    const int tid = threadIdx.x;
    const int wave = tid >> 6;
    const int lane = tid & 63;
    const int g = lane & 15;           // col group within strip
    const int s = lane >> 4;           // row sub within strip

    const int task = blockIdx.x * WPB + wave;
    const int plane = task / (XSTRIPS * YSTRIPS);
    const int rem = task - plane * (XSTRIPS * YSTRIPS);
    const int wy = rem / XSTRIPS;
    const int wx = rem - wy * XSTRIPS;

    const float* p1 = img1 + (size_t)plane * (IMH * IMW);
    const float* p2 = img2 + (size_t)plane * (IMH * IMW);

    const int x0 = wx * STRIPW;                     // strip's output col base
    int colbase = x0 + 4 * g;                       // this lane's input col base
    colbase = colbase <= IMW - 4 ? colbase : IMW - 4;  // clamp (masked outputs only)
    const int ys = wy * STRIPH + s * SUBH;          // first output row of this sub

    // constants from range flags
    float maxv = flags[0] ? 255.f : 1.f;
    float minv = flags[1] ? -1.f : 0.f;
    float L = maxv - minv;
    float C1 = (0.01f * L) * (0.01f * L);
    float C2 = (0.03f * L) * (0.03f * L);

    // ---- prime the 11-row ring (s,d) with rows ys .. ys+9 ----
    f32x4 rs[WS], rd[WS];
    #pragma unroll
    for (int k = 0; k < WS - 1; ++k) {
        int row = ys + k; row = row < IMH - 1 ? row : IMH - 1;
        const float* r1 = p1 + (size_t)row * IMW + colbase;
        const float* r2 = p2 + (size_t)row * IMW + colbase;
        f32x4 a = *reinterpret_cast<const f32x4*>(r1);
        f32x4 b = *reinterpret_cast<const f32x4*>(r2);
        rs[k] = a + b;
        rd[k] = a - b;
    }

    f32x4 acc4 = 0.f;    // per-column accumulators; masks applied after loop

    #pragma unroll
    for (int i = 0; i < SUBH; ++i) {
        // load row ys+i+10 into ring slot 10
        {
            int row = ys + i + (WS - 1); row = row < IMH - 1 ? row : IMH - 1;
            const float* r1 = p1 + (size_t)row * IMW + colbase;
            const float* r2 = p2 + (size_t)row * IMW + colbase;
            f32x4 a = *reinterpret_cast<const f32x4*>(r1);
            f32x4 b = *reinterpret_cast<const f32x4*>(r2);
            rs[WS - 1] = a + b;
            rd[WS - 1] = a - b;
        }

        // ---- vertical 11-tap conv of {s, d, s^2, d^2} (registers only) ----
        f32x4 S = 0.f, D = 0.f, P = 0.f, Q = 0.f;
        #pragma unroll
        for (int k = 0; k < WS; ++k) {
            float w = gw.g[k];
            f32x4 sv = rs[k], dv = rd[k];
            S += w * sv;
            D += w * dv;
            P += w * (sv * sv);
            Q += w * (dv * dv);
        }

        // ---- shift ring (SSA renames under full unroll) ----
        #pragma unroll
        for (int k = 0; k < WS - 1; ++k) { rs[k] = rs[k + 1]; rd[k] = rd[k + 1]; }

        // ---- horizontal windows: own values, then ALL shuffles batched ----
        float W[4][14];
        #pragma unroll
        for (int q = 0; q < 4; ++q) {
            f32x4 v = (q == 0) ? S : (q == 1) ? D : (q == 2) ? P : Q;
            #pragma unroll
            for (int j = 0; j < 4; ++j) W[q][j] = v[j];
        }
        #pragma unroll
        for (int q = 0; q < 4; ++q) {
            f32x4 v = (q == 0) ? S : (q == 1) ? D : (q == 2) ? P : Q;
            #pragma unroll
            for (int j = 0; j < 4; ++j) W[q][4 + j]  = __shfl(v[j], lane + 1, 64);
            #pragma unroll
            for (int j = 0; j < 4; ++j) W[q][8 + j]  = __shfl(v[j], lane + 2, 64);
            #pragma unroll
            for (int j = 0; j < 2; ++j) W[q][12 + j] = __shfl(v[j], lane + 3, 64);
        }

        // ---- horizontal 11-tap conv (4 quantities x 4 outputs) ----
        float hs[4][4];
        #pragma unroll
        for (int q = 0; q < 4; ++q) {
            #pragma unroll
            for (int c = 0; c < 4; ++c) {
                float acc = 0.f;
                #pragma unroll
                for (int k = 0; k < WS; ++k) acc += gw.g[k] * W[q][c + k];
                hs[q][c] = acc;
            }
        }

        // ---- SSIM map from 4-quantity form; row-masked accumulate ----
        const int oy = ys + i;
        float rowm = (oy < OH) ? 1.f : 0.f;
        #pragma unroll
        for (int c = 0; c < 4; ++c) {
            float hS = hs[0][c], hD = hs[1][c], Pv = hs[2][c], Qv = hs[3][c];
            float hS2 = hS * hS, hD2 = hD * hD;
            float mu12_2 = (hS2 - hD2) * 0.5f;   // 2*mu1*mu2
            float msq    = (hS2 + hD2) * 0.5f;   // mu1^2 + mu2^2
            float exy2   = (Pv - Qv) * 0.5f;     // 2*E[xy]
            float es     = (Pv + Qv) * 0.5f;     // E[x^2] + E[y^2]
            float v1 = (exy2 - mu12_2) + C2;     // 2*sigma12 + C2
            float v2 = (es - msq) + C2;          // sigma1+sigma2 + C2
            float num = (mu12_2 + C1) * v1;
            float den = (msq + C1) * v2;
            float rc = __builtin_amdgcn_rcpf(den);   // ~1 ulp, sufficient
            acc4[c] = fmaf(num * rc, rowm, acc4[c]);
        }
    }

    // ---- apply column masks once, then wave reduction ----
    float local = 0.f;
    #pragma unroll
    for (int c = 0; c < 4; ++c) {
        float cm = (g < 12 && (x0 + 4 * g + c) < OW) ? 1.f : 0.f;
        local = fmaf(acc4[c], cm, local);
    }

    #pragma unroll
    for (int off = 32; off > 0; off >>= 1)
        local += __shfl_down(local, off, 64);

    if (lane == 0) {
        if (use_partials) partials[task] = (double)local;
        else atomicAdd(sum_out, (double)local);
    }
}

// ---------------- kernel 3: final reduce + mean ----------------
__global__ __launch_bounds__(256) void reduce_kernel(const double* __restrict__ sum,
                                                     const double* __restrict__ partials,
                                                     int use_partials,
                                                     float* __restrict__ out) {
    if (use_partials) {
        double local = 0.0;
        for (int i = threadIdx.x; i < NTASKS; i += 256) local += partials[i];
        #pragma unroll
        for (int off = 32; off > 0; off >>= 1)
            local += __shfl_down(local, off, 64);
        __shared__ double ws2[4];
        int wave = threadIdx.x >> 6, lane = threadIdx.x & 63;
        if (lane == 0) ws2[wave] = local;
        __syncthreads();
        if (threadIdx.x == 0)
            out[0] = (float)((ws2[0] + ws2[1] + ws2[2] + ws2[3]) / (double)NOUT);
    } else {
        if (threadIdx.x == 0) out[0] = (float)(sum[0] / (double)NOUT);
    }
}

extern "C" void kernel_launch(void* const* d_in, const int* in_sizes, int n_in,
                              void* d_out, int out_size, void* d_ws, size_t ws_size,
                              hipStream_t stream) {
    const float* img1 = (const float*)d_in[0];
    const float* img2 = (const float*)d_in[1];
    float* out = (float*)d_out;

    // ws layout: [0..7] flags, [8..15] double sum, [16..] per-task partials
    unsigned* flags = (unsigned*)d_ws;
    double* sum = (double*)((char*)d_ws + 8);
    double* partials = (double*)((char*)d_ws + 16);
    int use_partials = (ws_size >= 16 + (size_t)NTASKS * sizeof(double)) ? 1 : 0;

    hipMemsetAsync(d_ws, 0, 16, stream);

    // Gaussian taps (float64 math then cast, matching numpy reference)
    GaussW gw;
    {
        double g[WS], ssum = 0.0;
        for (int i = 0; i < WS; ++i) {
            double x = (double)(i - WS / 2);
            g[i] = exp(-(x * x) / (2.0 * 1.5 * 1.5));
            ssum += g[i];
        }
        for (int i = 0; i < WS; ++i) gw.g[i] = (float)(g[i] / ssum);
    }

    int n = in_sizes[0];           // 25,165,824 floats
    flags_kernel<<<2048, 256, 0, stream>>>(img1, flags, n / 4);

    ssim_kernel<<<NBLK, 256, 0, stream>>>(img1, img2, flags, sum, partials, use_partials, gw);

    reduce_kernel<<<1, 256, 0, stream>>>(sum, partials, use_partials, out);
}

// Round 11
// 145.762 us; speedup vs baseline: 6.1150x; 6.1150x over previous
//
#include <hip/hip_runtime.h>
#include <cmath>

#define WS 11
#define IMH 512
#define IMW 512
#define OH 502
#define OW 502
#define NPLANES 96                 // 32 * 3
#define STRIPW 48                  // output cols per wave strip
#define STRIPH 64                  // output rows per wave strip (4 subs x 16)
#define SUBH 16                    // rows per lane
#define XSTRIPS 11                 // ceil(502/48)
#define YSTRIPS 8                  // ceil(502/64)
#define NTASKS (XSTRIPS * YSTRIPS * NPLANES)   // 8448
#define WPB 4                      // waves per block (256 threads), 1 strip/wave
#define NBLK (NTASKS / WPB)        // 2112
#define NOUT ((long long)NPLANES * OH * OW)    // 24192384

typedef float f32x4 __attribute__((ext_vector_type(4)));

struct GaussW { float g[WS]; };

// ---------------- kernel 1: range-detection flags over img1 ----------------
__global__ __launch_bounds__(256) void flags_kernel(const float* __restrict__ img1,
                                                    unsigned* __restrict__ flags,
                                                    int n4) {
    int idx = blockIdx.x * blockDim.x + threadIdx.x;
    int stride = gridDim.x * blockDim.x;
    int gt = 0, lt = 0;
    const float4* p = reinterpret_cast<const float4*>(img1);
    for (int i = idx; i < n4; i += stride) {
        float4 v = p[i];
        gt |= (v.x > 128.f) | (v.y > 128.f) | (v.z > 128.f) | (v.w > 128.f);
        lt |= (v.x < -0.5f) | (v.y < -0.5f) | (v.z < -0.5f) | (v.w < -0.5f);
    }
    if (gt) atomicOr(&flags[0], 1u);
    if (lt) atomicOr(&flags[1], 1u);
}

// ---------------- kernel 2: LDS-free register-ring SSIM, 4-quantity form ----
// EXACT R8 per-wave body (VGPR 112, no spills). One strip (48x64) per wave;
// 4 independent waves per 256-thread block — only change vs R8 is block
// size, to double wave-payload per dispatch slot (residency was
// dispatch-rate-limited at 128 threads). No launch_bounds min-waves (R10
// lesson: forced caps -> spills). Per-quantity Wq[14] shuffle window (R10
// lesson: batching all 4 quantities' windows blows the live set).
__global__ __launch_bounds__(256) void ssim_kernel(const float* __restrict__ img1,
                                                   const float* __restrict__ img2,
                                                   const unsigned* __restrict__ flags,
                                                   double* __restrict__ sum_out,
                                                   double* __restrict__ partials,
                                                   int use_partials,
                                                   GaussW gw) {
    const int tid = threadIdx.x;
    const int wave = tid >> 6;
    const int lane = tid & 63;
    const int g = lane & 15;           // col group within strip
    const int s = lane >> 4;           // row sub within strip

    const int task = blockIdx.x * WPB + wave;
    const int plane = task / (XSTRIPS * YSTRIPS);
    const int rem = task - plane * (XSTRIPS * YSTRIPS);
    const int wy = rem / XSTRIPS;
    const int wx = rem - wy * XSTRIPS;

    const float* p1 = img1 + (size_t)plane * (IMH * IMW);
    const float* p2 = img2 + (size_t)plane * (IMH * IMW);

    const int x0 = wx * STRIPW;                     // strip's output col base
    int colbase = x0 + 4 * g;                       // this lane's input col base
    colbase = colbase <= IMW - 4 ? colbase : IMW - 4;  // clamp (masked outputs only)
    const int ys = wy * STRIPH + s * SUBH;          // first output row of this sub

    // constants from range flags
    float maxv = flags[0] ? 255.f : 1.f;
    float minv = flags[1] ? -1.f : 0.f;
    float L = maxv - minv;
    float C1 = (0.01f * L) * (0.01f * L);
    float C2 = (0.03f * L) * (0.03f * L);

    // ---- prime the 11-row ring (s,d) with rows ys .. ys+9 ----
    f32x4 rs[WS], rd[WS];
    #pragma unroll
    for (int k = 0; k < WS - 1; ++k) {
        int row = ys + k; row = row < IMH - 1 ? row : IMH - 1;
        const float* r1 = p1 + (size_t)row * IMW + colbase;
        const float* r2 = p2 + (size_t)row * IMW + colbase;
        f32x4 a = *reinterpret_cast<const f32x4*>(r1);
        f32x4 b = *reinterpret_cast<const f32x4*>(r2);
        rs[k] = a + b;
        rd[k] = a - b;
    }

    f32x4 acc4 = 0.f;    // per-column accumulators; masks applied after loop

    #pragma unroll
    for (int i = 0; i < SUBH; ++i) {
        // load row ys+i+10 into ring slot 10
        {
            int row = ys + i + (WS - 1); row = row < IMH - 1 ? row : IMH - 1;
            const float* r1 = p1 + (size_t)row * IMW + colbase;
            const float* r2 = p2 + (size_t)row * IMW + colbase;
            f32x4 a = *reinterpret_cast<const f32x4*>(r1);
            f32x4 b = *reinterpret_cast<const f32x4*>(r2);
            rs[WS - 1] = a + b;
            rd[WS - 1] = a - b;
        }

        // ---- vertical 11-tap conv of {s, d, s^2, d^2} (registers only) ----
        f32x4 S = 0.f, D = 0.f, P = 0.f, Q = 0.f;
        #pragma unroll
        for (int k = 0; k < WS; ++k) {
            float w = gw.g[k];
            f32x4 sv = rs[k], dv = rd[k];
            S += w * sv;
            D += w * dv;
            P += w * (sv * sv);
            Q += w * (dv * dv);
        }

        // ---- shift ring (SSA renames under full unroll) ----
        #pragma unroll
        for (int k = 0; k < WS - 1; ++k) { rs[k] = rs[k + 1]; rd[k] = rd[k + 1]; }

        // ---- horizontal 11-tap conv via cross-lane shuffles (4 quantities) ----
        float hs[4][4];
        #pragma unroll
        for (int q = 0; q < 4; ++q) {
            f32x4 v = (q == 0) ? S : (q == 1) ? D : (q == 2) ? P : Q;
            float Wq[14];
            #pragma unroll
            for (int j = 0; j < 4; ++j) Wq[j] = v[j];
            #pragma unroll
            for (int j = 0; j < 4; ++j) Wq[4 + j]  = __shfl(v[j], lane + 1, 64);
            #pragma unroll
            for (int j = 0; j < 4; ++j) Wq[8 + j]  = __shfl(v[j], lane + 2, 64);
            #pragma unroll
            for (int j = 0; j < 2; ++j) Wq[12 + j] = __shfl(v[j], lane + 3, 64);
            #pragma unroll
            for (int c = 0; c < 4; ++c) {
                float acc = 0.f;
                #pragma unroll
                for (int k = 0; k < WS; ++k) acc += gw.g[k] * Wq[c + k];
                hs[q][c] = acc;
            }
        }

        // ---- SSIM map from 4-quantity form; row-masked accumulate ----
        const int oy = ys + i;
        float rowm = (oy < OH) ? 1.f : 0.f;
        #pragma unroll
        for (int c = 0; c < 4; ++c) {
            float hS = hs[0][c], hD = hs[1][c], Pv = hs[2][c], Qv = hs[3][c];
            float hS2 = hS * hS, hD2 = hD * hD;
            float mu12_2 = (hS2 - hD2) * 0.5f;   // 2*mu1*mu2
            float msq    = (hS2 + hD2) * 0.5f;   // mu1^2 + mu2^2
            float exy2   = (Pv - Qv) * 0.5f;     // 2*E[xy]
            float es     = (Pv + Qv) * 0.5f;     // E[x^2] + E[y^2]
            float v1 = (exy2 - mu12_2) + C2;     // 2*sigma12 + C2
            float v2 = (es - msq) + C2;          // sigma1+sigma2 + C2
            float num = (mu12_2 + C1) * v1;
            float den = (msq + C1) * v2;
            float rc = __builtin_amdgcn_rcpf(den);   // ~1 ulp, sufficient
            acc4[c] = fmaf(num * rc, rowm, acc4[c]);
        }
    }

    // ---- apply column masks once, then wave reduction ----
    float local = 0.f;
    #pragma unroll
    for (int c = 0; c < 4; ++c) {
        float cm = (g < 12 && (x0 + 4 * g + c) < OW) ? 1.f : 0.f;
        local = fmaf(acc4[c], cm, local);
    }

    #pragma unroll
    for (int off = 32; off > 0; off >>= 1)
        local += __shfl_down(local, off, 64);

    if (lane == 0) {
        if (use_partials) partials[task] = (double)local;
        else atomicAdd(sum_out, (double)local);
    }
}

// ---------------- kernel 3: final reduce + mean ----------------
__global__ __launch_bounds__(256) void reduce_kernel(const double* __restrict__ sum,
                                                     const double* __restrict__ partials,
                                                     int use_partials,
                                                     float* __restrict__ out) {
    if (use_partials) {
        double local = 0.0;
        for (int i = threadIdx.x; i < NTASKS; i += 256) local += partials[i];
        #pragma unroll
        for (int off = 32; off > 0; off >>= 1)
            local += __shfl_down(local, off, 64);
        __shared__ double ws2[4];
        int wave = threadIdx.x >> 6, lane = threadIdx.x & 63;
        if (lane == 0) ws2[wave] = local;
        __syncthreads();
        if (threadIdx.x == 0)
            out[0] = (float)((ws2[0] + ws2[1] + ws2[2] + ws2[3]) / (double)NOUT);
    } else {
        if (threadIdx.x == 0) out[0] = (float)(sum[0] / (double)NOUT);
    }
}

extern "C" void kernel_launch(void* const* d_in, const int* in_sizes, int n_in,
                              void* d_out, int out_size, void* d_ws, size_t ws_size,
                              hipStream_t stream) {
    const float* img1 = (const float*)d_in[0];
    const float* img2 = (const float*)d_in[1];
    float* out = (float*)d_out;

    // ws layout: [0..7] flags, [8..15] double sum, [16..] per-task partials
    unsigned* flags = (unsigned*)d_ws;
    double* sum = (double*)((char*)d_ws + 8);
    double* partials = (double*)((char*)d_ws + 16);
    int use_partials = (ws_size >= 16 + (size_t)NTASKS * sizeof(double)) ? 1 : 0;

    hipMemsetAsync(d_ws, 0, 16, stream);

    // Gaussian taps (float64 math then cast, matching numpy reference)
    GaussW gw;
    {
        double g[WS], ssum = 0.0;
        for (int i = 0; i < WS; ++i) {
            double x = (double)(i - WS / 2);
            g[i] = exp(-(x * x) / (2.0 * 1.5 * 1.5));
            ssum += g[i];
        }
        for (int i = 0; i < WS; ++i) gw.g[i] = (float)(g[i] / ssum);
    }

    int n = in_sizes[0];           // 25,165,824 floats
    flags_kernel<<<2048, 256, 0, stream>>>(img1, flags, n / 4);

    ssim_kernel<<<NBLK, 256, 0, stream>>>(img1, img2, flags, sum, partials, use_partials, gw);

    reduce_kernel<<<1, 256, 0, stream>>>(sum, partials, use_partials, out);
}